// Round 11
// baseline (883.996 us; speedup 1.0000x reference)
//
#include <hip/hip_runtime.h>
#include <hip/hip_bf16.h>

typedef __attribute__((ext_vector_type(8))) short short8;
typedef __attribute__((ext_vector_type(4))) float f32x4;

#define N_U 8192
#define N_I 8192
#define KD  256

// ws float-slot layout: [0,4096) gemm err; [4096,4608) pack_a; [4608,6656)
// pack_v; [8192,24576) probe_kloop; [24576,40960) probe_rtile;
// [40960,49152) probe_rideal. Abf at byte 1MiB, Vbf at 5MiB.
#define ERR_SLOTS 4096
#define REGA_BASE 4096
#define REGV_BASE 4608
#define SLOTS_END 6656
#define PR_KLOOP  8192
#define PR_RTILE  24576
#define PR_RIDEAL 40960

// global_load_lds, 16B per lane.
#define GLD16(g, l) __builtin_amdgcn_global_load_lds( \
    (const __attribute__((address_space(1))) unsigned int*)(unsigned long long)(uintptr_t)(g), \
    (__attribute__((address_space(3))) unsigned int*)(unsigned int)(uintptr_t)(l), 16, 0, 0)

static __device__ __forceinline__ unsigned short f2bf(float x) {
  unsigned u = __builtin_bit_cast(unsigned, x);
  u += 0x7fffu + ((u >> 16) & 1u);   // round-to-nearest-even
  return (unsigned short)(u >> 16);
}

static __device__ __forceinline__ void block_reduce_store(float v, float* slot) {
  #pragma unroll
  for (int off = 32; off > 0; off >>= 1) v += __shfl_down(v, off, 64);
  __shared__ float red[4];
  int lane = threadIdx.x & 63, wv = threadIdx.x >> 6;
  if (lane == 0) red[wv] = v;
  __syncthreads();
  if (threadIdx.x == 0) *slot = red[0] + red[1] + red[2] + red[3];
}

// ---------------- real kernels (verbatim R6 structure, best known) --------

__global__ __launch_bounds__(256) void pack_a_kernel(
    const float* __restrict__ U, const float* __restrict__ P,
    unsigned short* __restrict__ Abf, float* __restrict__ ws)
{
  __shared__ float Pt[64][65];   // +1 pad
  const int u0 = blockIdx.x * 64;
  const int k0 = blockIdx.y * 64;
  const int t = threadIdx.x;
  float ss = 0.f;
  {
    const int ul4 = (t & 15) * 4, klb = t >> 4;
    #pragma unroll
    for (int pass = 0; pass < 4; ++pass) {
      int kl = klb + pass * 16;
      float4 pv = *(const float4*)&P[(size_t)(k0 + kl) * N_U + u0 + ul4];
      Pt[kl][ul4 + 0] = pv.x; Pt[kl][ul4 + 1] = pv.y;
      Pt[kl][ul4 + 2] = pv.z; Pt[kl][ul4 + 3] = pv.w;
      ss += pv.x * pv.x + pv.y * pv.y + pv.z * pv.z + pv.w * pv.w;
    }
  }
  __syncthreads();
  {
    const int k4 = (t & 15) * 4, ulb = t >> 4;
    #pragma unroll
    for (int pass = 0; pass < 4; ++pass) {
      int ul = ulb + pass * 16;
      float4 uv = *(const float4*)&U[(size_t)(u0 + ul) * KD + k0 + k4];
      ss += uv.x * uv.x + uv.y * uv.y + uv.z * uv.z + uv.w * uv.w;
      ushort4 w;
      w.x = f2bf(uv.x * Pt[k4 + 0][ul]);
      w.y = f2bf(uv.y * Pt[k4 + 1][ul]);
      w.z = f2bf(uv.z * Pt[k4 + 2][ul]);
      w.w = f2bf(uv.w * Pt[k4 + 3][ul]);
      *(ushort4*)&Abf[(size_t)(u0 + ul) * KD + k0 + k4] = w;
    }
  }
  block_reduce_store(ss, ws + REGA_BASE + blockIdx.y * 128 + blockIdx.x);
}

__global__ __launch_bounds__(256) void pack_v_kernel(
    const float* __restrict__ V, unsigned short* __restrict__ Vbf,
    float* __restrict__ ws)
{
  size_t i = ((size_t)blockIdx.x * 256 + threadIdx.x) * 4;
  float4 v = *(const float4*)&V[i];
  float ss = v.x * v.x + v.y * v.y + v.z * v.z + v.w * v.w;
  ushort4 w;
  w.x = f2bf(v.x); w.y = f2bf(v.y); w.z = f2bf(v.z); w.w = f2bf(v.w);
  *(ushort4*)&Vbf[i] = w;
  block_reduce_store(ss, ws + REGV_BASE + blockIdx.x);
}

__global__ __launch_bounds__(256) void gemm_loss_kernel(
    const float* __restrict__ R, const unsigned short* __restrict__ Abf,
    const unsigned short* __restrict__ Vbf, float* __restrict__ ws)
{
  __shared__ unsigned short As[128 * 32];   // 8 KB
  __shared__ unsigned short Bs[128 * 32];   // 8 KB
  const int tid = threadIdx.x;
  const int wv = tid >> 6, lane = tid & 63;
  const int brow = blockIdx.x, bcol = blockIdx.y;
  const int wr = wv >> 1, wc = wv & 1;

  f32x4 acc[4][4] = {};

  const unsigned short* Ag = Abf + (size_t)brow * 128 * KD;
  const unsigned short* Bg = Vbf + (size_t)bcol * 128 * KD;
  const int f0 = wv * 128 + lane;
  const int f1 = f0 + 64;
  const int r0 = lane & 15, kc = (lane >> 4) * 8;

  for (int kt = 0; kt < KD; kt += 32) {
    __syncthreads();
    GLD16(Ag + ((f0 >> 2) * KD + kt + (f0 & 3) * 8), &As[f0 * 8]);
    GLD16(Bg + ((f0 >> 2) * KD + kt + (f0 & 3) * 8), &Bs[f0 * 8]);
    GLD16(Ag + ((f1 >> 2) * KD + kt + (f1 & 3) * 8), &As[f1 * 8]);
    GLD16(Bg + ((f1 >> 2) * KD + kt + (f1 & 3) * 8), &Bs[f1 * 8]);
    __syncthreads();
    short8 a[4], b[4];
    #pragma unroll
    for (int m = 0; m < 4; ++m)
      a[m] = *(const short8*)&As[(wr * 64 + m * 16 + r0) * 32 + kc];
    #pragma unroll
    for (int n = 0; n < 4; ++n)
      b[n] = *(const short8*)&Bs[(wc * 64 + n * 16 + r0) * 32 + kc];
    #pragma unroll
    for (int m = 0; m < 4; ++m)
      #pragma unroll
      for (int n = 0; n < 4; ++n)
        acc[m][n] = __builtin_amdgcn_mfma_f32_16x16x32_bf16(b[n], a[m], acc[m][n], 0, 0, 0);
  }

  float lsum = 0.f;
  const int row0 = brow * 128 + wr * 64 + (lane & 15);
  const size_t col0 = (size_t)bcol * 128 + wc * 64 + (lane >> 4) * 4;
  #pragma unroll
  for (int m = 0; m < 4; ++m) {
    const float* rp = R + (size_t)(row0 + m * 16) * N_I + col0;
    #pragma unroll
    for (int n = 0; n < 4; ++n) {
      float4 rv = *(const float4*)&rp[n * 16];
      if (rv.x != 0.f) { float d = rv.x - acc[m][n][0]; lsum += d * d; }
      if (rv.y != 0.f) { float d = rv.y - acc[m][n][1]; lsum += d * d; }
      if (rv.z != 0.f) { float d = rv.z - acc[m][n][2]; lsum += d * d; }
      if (rv.w != 0.f) { float d = rv.w - acc[m][n][3]; lsum += d * d; }
    }
  }

  #pragma unroll
  for (int off = 32; off > 0; off >>= 1) lsum += __shfl_down(lsum, off, 64);
  float* red = (float*)As;
  __syncthreads();
  if (lane == 0) red[wv] = lsum;
  __syncthreads();
  if (tid == 0) ws[blockIdx.y * 64 + blockIdx.x] = red[0] + red[1] + red[2] + red[3];
}

__global__ __launch_bounds__(256) void finalize_kernel(
    const float* __restrict__ ws, float* __restrict__ out)
{
  __shared__ float sh[256];
  const int tid = threadIdx.x;
  float e = 0.f, r = 0.f;
  for (int i = tid; i < ERR_SLOTS; i += 256) e += ws[i];
  for (int i = REGA_BASE + tid; i < SLOTS_END; i += 256) r += ws[i];
  sh[tid] = 0.5f * e + 0.05f * r;
  __syncthreads();
  #pragma unroll
  for (int s = 128; s > 0; s >>= 1) {
    if (tid < s) sh[tid] += sh[tid + s];
    __syncthreads();
  }
  if (tid == 0) out[0] = sh[0];
}

// ---------------- probes (write ONLY dummy slots; 6 internal reps each) ---

// P1: R6 K-loop only (stage+MFMA). Measures staging/MFMA phase in isolation.
__global__ __launch_bounds__(256) void probe_kloop(
    const unsigned short* __restrict__ Abf, const unsigned short* __restrict__ Vbf,
    float* __restrict__ ws)
{
  __shared__ unsigned short As[128 * 32];
  __shared__ unsigned short Bs[128 * 32];
  const int tid = threadIdx.x;
  const int wv = tid >> 6, lane = tid & 63;
  const int brow = blockIdx.x, bcol = blockIdx.y;
  const int wr = wv >> 1, wc = wv & 1;
  f32x4 acc[4][4] = {};
  const unsigned short* Ag = Abf + (size_t)brow * 128 * KD;
  const unsigned short* Bg = Vbf + (size_t)bcol * 128 * KD;
  const int f0 = wv * 128 + lane;
  const int f1 = f0 + 64;
  const int r0 = lane & 15, kc = (lane >> 4) * 8;

  #pragma unroll 1
  for (int rep = 0; rep < 6; ++rep) {
    for (int kt = 0; kt < KD; kt += 32) {
      __syncthreads();
      GLD16(Ag + ((f0 >> 2) * KD + kt + (f0 & 3) * 8), &As[f0 * 8]);
      GLD16(Bg + ((f0 >> 2) * KD + kt + (f0 & 3) * 8), &Bs[f0 * 8]);
      GLD16(Ag + ((f1 >> 2) * KD + kt + (f1 & 3) * 8), &As[f1 * 8]);
      GLD16(Bg + ((f1 >> 2) * KD + kt + (f1 & 3) * 8), &Bs[f1 * 8]);
      __syncthreads();
      short8 a[4], b[4];
      #pragma unroll
      for (int m = 0; m < 4; ++m)
        a[m] = *(const short8*)&As[(wr * 64 + m * 16 + r0) * 32 + kc];
      #pragma unroll
      for (int n = 0; n < 4; ++n)
        b[n] = *(const short8*)&Bs[(wc * 64 + n * 16 + r0) * 32 + kc];
      #pragma unroll
      for (int m = 0; m < 4; ++m)
        #pragma unroll
        for (int n = 0; n < 4; ++n)
          acc[m][n] = __builtin_amdgcn_mfma_f32_16x16x32_bf16(b[n], a[m], acc[m][n], 0, 0, 0);
    }
  }
  float s = 0.f;
  #pragma unroll
  for (int m = 0; m < 4; ++m)
    #pragma unroll
    for (int n = 0; n < 4; ++n)
      s += acc[m][n][0] + acc[m][n][1] + acc[m][n][2] + acc[m][n][3];
  #pragma unroll
  for (int off = 32; off > 0; off >>= 1) s += __shfl_down(s, off, 64);
  if (lane == 0) ws[PR_KLOOP + (((blockIdx.y * 64 + blockIdx.x) << 2) | wv)] = s;
}

// P2: R6's exact epilogue R-access pattern (16 rows x 64B granules/instr).
__global__ __launch_bounds__(256) void probe_rtile(
    const float* __restrict__ R, float* __restrict__ ws)
{
  const int tid = threadIdx.x;
  const int wv = tid >> 6, lane = tid & 63;
  const int brow = blockIdx.x, bcol0 = blockIdx.y;
  const int wr = wv >> 1, wc = wv & 1;
  float lsum = 0.f;
  #pragma unroll 1
  for (int rep = 0; rep < 6; ++rep) {
    const int bcol = (bcol0 + rep * 11) & 63;   // rotate: defeat CSE / L3 reuse
    const int row0 = brow * 128 + wr * 64 + (lane & 15);
    const size_t col0 = (size_t)bcol * 128 + wc * 64 + (lane >> 4) * 4;
    #pragma unroll
    for (int m = 0; m < 4; ++m) {
      const float* rp = R + (size_t)(row0 + m * 16) * N_I + col0;
      #pragma unroll
      for (int n = 0; n < 4; ++n) {
        float4 rv = *(const float4*)&rp[n * 16];
        if (rv.x != 0.f) lsum += rv.x * rv.x;
        if (rv.y != 0.f) lsum += rv.y * rv.y;
        if (rv.z != 0.f) lsum += rv.z * rv.z;
        if (rv.w != 0.f) lsum += rv.w * rv.w;
      }
    }
  }
  #pragma unroll
  for (int off = 32; off > 0; off >>= 1) lsum += __shfl_down(lsum, off, 64);
  if (lane == 0) ws[PR_RTILE + (((bcol0 * 64 + brow) << 2) | wv)] = lsum;
}

// P3: ideal coalesced grid-stride read of all 268MB of R.
__global__ __launch_bounds__(256) void probe_rideal(
    const float* __restrict__ R, float* __restrict__ ws)
{
  const size_t total4 = (size_t)N_U * N_I / 4;      // 2^24 float4s
  const size_t gstride = (size_t)gridDim.x * 256;
  const float4* R4 = (const float4*)R;
  const size_t g = (size_t)blockIdx.x * 256 + threadIdx.x;
  float lsum = 0.f;
  #pragma unroll 1
  for (int rep = 0; rep < 6; ++rep) {
    const size_t off = (size_t)rep * 2796203u;      // rotate start per rep
    for (size_t i = g; i < total4; i += gstride) {
      float4 rv = R4[(i + off) & (total4 - 1)];
      if (rv.x != 0.f) lsum += rv.x * rv.x;
      if (rv.y != 0.f) lsum += rv.y * rv.y;
      if (rv.z != 0.f) lsum += rv.z * rv.z;
      if (rv.w != 0.f) lsum += rv.w * rv.w;
    }
  }
  #pragma unroll
  for (int off = 32; off > 0; off >>= 1) lsum += __shfl_down(lsum, off, 64);
  const int wv = threadIdx.x >> 6, lane = threadIdx.x & 63;
  if (lane == 0) ws[PR_RIDEAL + ((blockIdx.x << 2) | wv)] = lsum;
}

extern "C" void kernel_launch(void* const* d_in, const int* in_sizes, int n_in,
                              void* d_out, int out_size, void* d_ws, size_t ws_size,
                              hipStream_t stream) {
  const float* R = (const float*)d_in[0];
  const float* U = (const float*)d_in[1];
  const float* V = (const float*)d_in[2];
  // d_in[3]=alpha, d_in[4]=Y, d_in[6]=Q: dead w.r.t. the returned value.
  const float* P = (const float*)d_in[5];

  float* ws = (float*)d_ws;                                      // slot region
  unsigned short* Abf = (unsigned short*)((char*)d_ws + (1 << 20));   // 4 MiB
  unsigned short* Vbf = Abf + (size_t)N_U * KD;                       // 4 MiB
  float* out = (float*)d_out;

  pack_a_kernel<<<dim3(N_U / 64, KD / 64), 256, 0, stream>>>(U, P, Abf, ws);
  pack_v_kernel<<<dim3((N_I * KD) / (256 * 4)), 256, 0, stream>>>(V, Vbf, ws);
  gemm_loss_kernel<<<dim3(64, 64), 256, 0, stream>>>(R, Abf, Vbf, ws);
  finalize_kernel<<<1, 256, 0, stream>>>(ws, out);

  // diagnostic probes (answer already finalized; dummy-slot writes only)
  probe_kloop<<<dim3(64, 64), 256, 0, stream>>>(Abf, Vbf, ws);
  probe_rtile<<<dim3(64, 64), 256, 0, stream>>>(R, ws);
  probe_rideal<<<2048, 256, 0, stream>>>(R, ws);
}

// Round 12
// 103.493 us; speedup vs baseline: 8.5416x; 8.5416x over previous
//
#include <hip/hip_runtime.h>
#include <hip/hip_bf16.h>

typedef __attribute__((ext_vector_type(8))) short short8;
typedef __attribute__((ext_vector_type(4))) float f32x4;

#define N_U 8192
#define N_I 8192
#define KD  256

// ws float-slot layout: [0,4096) gemm err; [4096,4608) pack_a; [4608,6656)
// pack_v. All written unconditionally every launch (plain stores, no atomics).
#define ERR_SLOTS 4096
#define REGA_BASE 4096
#define REGV_BASE 4608
#define SLOTS_END 6656

// global_load_lds, 16B per lane.
#define GLD16(g, l) __builtin_amdgcn_global_load_lds( \
    (const __attribute__((address_space(1))) unsigned int*)(unsigned long long)(uintptr_t)(g), \
    (__attribute__((address_space(3))) unsigned int*)(unsigned int)(uintptr_t)(l), 16, 0, 0)

static __device__ __forceinline__ unsigned short f2bf(float x) {
  unsigned u = __builtin_bit_cast(unsigned, x);
  u += 0x7fffu + ((u >> 16) & 1u);   // round-to-nearest-even
  return (unsigned short)(u >> 16);
}

static __device__ __forceinline__ void block_reduce_store(float v, float* slot) {
  #pragma unroll
  for (int off = 32; off > 0; off >>= 1) v += __shfl_down(v, off, 64);
  __shared__ float red[4];
  int lane = threadIdx.x & 63, wv = threadIdx.x >> 6;
  if (lane == 0) red[wv] = v;
  __syncthreads();
  if (threadIdx.x == 0) *slot = red[0] + red[1] + red[2] + red[3];
}

// A = P.T (elementwise*) U  -> bf16 [N_U][KD]; partial sum(U^2)+sum(P^2) to slot.
__global__ __launch_bounds__(256) void pack_a_kernel(
    const float* __restrict__ U, const float* __restrict__ P,
    unsigned short* __restrict__ Abf, float* __restrict__ ws)
{
  __shared__ float Pt[64][65];   // +1 pad
  const int u0 = blockIdx.x * 64;
  const int k0 = blockIdx.y * 64;
  const int t = threadIdx.x;
  float ss = 0.f;
  {
    const int ul4 = (t & 15) * 4, klb = t >> 4;
    #pragma unroll
    for (int pass = 0; pass < 4; ++pass) {
      int kl = klb + pass * 16;
      float4 pv = *(const float4*)&P[(size_t)(k0 + kl) * N_U + u0 + ul4];
      Pt[kl][ul4 + 0] = pv.x; Pt[kl][ul4 + 1] = pv.y;
      Pt[kl][ul4 + 2] = pv.z; Pt[kl][ul4 + 3] = pv.w;
      ss += pv.x * pv.x + pv.y * pv.y + pv.z * pv.z + pv.w * pv.w;
    }
  }
  __syncthreads();
  {
    const int k4 = (t & 15) * 4, ulb = t >> 4;
    #pragma unroll
    for (int pass = 0; pass < 4; ++pass) {
      int ul = ulb + pass * 16;
      float4 uv = *(const float4*)&U[(size_t)(u0 + ul) * KD + k0 + k4];
      ss += uv.x * uv.x + uv.y * uv.y + uv.z * uv.z + uv.w * uv.w;
      ushort4 w;
      w.x = f2bf(uv.x * Pt[k4 + 0][ul]);
      w.y = f2bf(uv.y * Pt[k4 + 1][ul]);
      w.z = f2bf(uv.z * Pt[k4 + 2][ul]);
      w.w = f2bf(uv.w * Pt[k4 + 3][ul]);
      *(ushort4*)&Abf[(size_t)(u0 + ul) * KD + k0 + k4] = w;
    }
  }
  block_reduce_store(ss, ws + REGA_BASE + blockIdx.y * 128 + blockIdx.x);
}

// V -> bf16; partial sum(V^2) to slot.
__global__ __launch_bounds__(256) void pack_v_kernel(
    const float* __restrict__ V, unsigned short* __restrict__ Vbf,
    float* __restrict__ ws)
{
  size_t i = ((size_t)blockIdx.x * 256 + threadIdx.x) * 4;
  float4 v = *(const float4*)&V[i];
  float ss = v.x * v.x + v.y * v.y + v.z * v.z + v.w * v.w;
  ushort4 w;
  w.x = f2bf(v.x); w.y = f2bf(v.y); w.z = f2bf(v.z); w.w = f2bf(v.w);
  *(ushort4*)&Vbf[i] = w;
  block_reduce_store(ss, ws + REGV_BASE + blockIdx.x);
}

// 128x128 tile, BK=32, 4 waves (2x2), swapped-operand mfma.
// R12: (a) LDS k-slot XOR swizzle — chunk (row,ks) stored at LDS position
//   row*4 + (ks ^ ((row>>1)&3)); source pre-swizzled in STAGE (linear GLD
//   dest, rule-21 compliant), read applies the same XOR. Kills the 8-way
//   ds_read_b128 bank conflict found by probe_kloop (2.5e7 conflict cycles).
// (b) double-buffered LDS + ONE vmcnt(0)+s_barrier per iter (minimum-2-phase
//   recipe) instead of two full __syncthreads drains.
__global__ __launch_bounds__(256) void gemm_loss_kernel(
    const float* __restrict__ R, const unsigned short* __restrict__ Abf,
    const unsigned short* __restrict__ Vbf, float* __restrict__ ws)
{
  __shared__ unsigned short As[2][128 * 32];   // 16 KB
  __shared__ unsigned short Bs[2][128 * 32];   // 16 KB
  const int tid = threadIdx.x;
  const int wv = tid >> 6, lane = tid & 63;
  const int brow = blockIdx.x, bcol = blockIdx.y;
  const int wr = wv >> 1, wc = wv & 1;

  f32x4 acc[4][4] = {};

  const unsigned short* Ag = Abf + (size_t)brow * 128 * KD;
  const unsigned short* Bg = Vbf + (size_t)bcol * 128 * KD;
  const int f0 = wv * 128 + lane;   // LDS chunk positions; f0,f1 cover [0,512)
  const int f1 = f0 + 64;
  // source k-slot for position f: ks = (f&3) ^ ((f>>3)&3)  (shorts offset *8)
  const int sw0 = (((f0 & 3) ^ ((f0 >> 3) & 3)) * 8);
  const int sw1 = (((f1 & 3) ^ ((f1 >> 3) & 3)) * 8);
  const int r0 = lane & 15;
  // read-side: k-slot ks0=lane>>4 of row r lives at (r*4 + (ks0^((r0>>1)&3)))*8
  const int kq = ((lane >> 4) ^ ((r0 >> 1) & 3)) * 8;

#define STAGE(buf, kt) do { \
    GLD16(Ag + ((f0 >> 2) * KD + (kt)) + sw0, &As[buf][f0 * 8]); \
    GLD16(Bg + ((f0 >> 2) * KD + (kt)) + sw0, &Bs[buf][f0 * 8]); \
    GLD16(Ag + ((f1 >> 2) * KD + (kt)) + sw1, &As[buf][f1 * 8]); \
    GLD16(Bg + ((f1 >> 2) * KD + (kt)) + sw1, &Bs[buf][f1 * 8]); \
  } while (0)

  STAGE(0, 0);
  asm volatile("s_waitcnt vmcnt(0)" ::: "memory");
  __builtin_amdgcn_s_barrier();

  #pragma unroll
  for (int t = 0; t < 7; ++t) {
    const int cur = t & 1;
    STAGE(cur ^ 1, (t + 1) * 32);
    short8 a[4], b[4];
    #pragma unroll
    for (int m = 0; m < 4; ++m)
      a[m] = *(const short8*)&As[cur][(wr * 64 + m * 16 + r0) * 32 + kq];
    #pragma unroll
    for (int n = 0; n < 4; ++n)
      b[n] = *(const short8*)&Bs[cur][(wc * 64 + n * 16 + r0) * 32 + kq];
    #pragma unroll
    for (int m = 0; m < 4; ++m)
      #pragma unroll
      for (int n = 0; n < 4; ++n)
        acc[m][n] = __builtin_amdgcn_mfma_f32_16x16x32_bf16(b[n], a[m], acc[m][n], 0, 0, 0);
    // next-tile staging complete; reads of buf[cur] already consumed (lgkmcnt
    // enforced before MFMA issue) -> safe to re-stage cur at t+1.
    asm volatile("s_waitcnt vmcnt(0)" ::: "memory");
    __builtin_amdgcn_s_barrier();
  }
#undef STAGE

  // t = 7 (buf 1), no further staging, no trailing barrier needed.
  {
    short8 a[4], b[4];
    #pragma unroll
    for (int m = 0; m < 4; ++m)
      a[m] = *(const short8*)&As[1][(wr * 64 + m * 16 + r0) * 32 + kq];
    #pragma unroll
    for (int n = 0; n < 4; ++n)
      b[n] = *(const short8*)&Bs[1][(wc * 64 + n * 16 + r0) * 32 + kq];
    #pragma unroll
    for (int m = 0; m < 4; ++m)
      #pragma unroll
      for (int n = 0; n < 4; ++n)
        acc[m][n] = __builtin_amdgcn_mfma_f32_16x16x32_bf16(b[n], a[m], acc[m][n], 0, 0, 0);
  }

  // Epilogue (R6-verified mapping):
  //   pred_row = brow*128 + wr*64 + m*16 + (lane&15)
  //   pred_col = bcol*128 + wc*64 + n*16 + (lane>>4)*4 + j
  float lsum = 0.f;
  const int row0 = brow * 128 + wr * 64 + (lane & 15);
  const size_t col0 = (size_t)bcol * 128 + wc * 64 + (lane >> 4) * 4;
  #pragma unroll
  for (int m = 0; m < 4; ++m) {
    const float* rp = R + (size_t)(row0 + m * 16) * N_I + col0;
    #pragma unroll
    for (int n = 0; n < 4; ++n) {
      float4 rv = *(const float4*)&rp[n * 16];
      if (rv.x != 0.f) { float d = rv.x - acc[m][n][0]; lsum += d * d; }
      if (rv.y != 0.f) { float d = rv.y - acc[m][n][1]; lsum += d * d; }
      if (rv.z != 0.f) { float d = rv.z - acc[m][n][2]; lsum += d * d; }
      if (rv.w != 0.f) { float d = rv.w - acc[m][n][3]; lsum += d * d; }
    }
  }

  // block reduce, reusing As (buf0, fully consumed) as scratch.
  #pragma unroll
  for (int off = 32; off > 0; off >>= 1) lsum += __shfl_down(lsum, off, 64);
  float* red = (float*)As;
  __syncthreads();
  if (lane == 0) red[wv] = lsum;
  __syncthreads();
  if (tid == 0) ws[blockIdx.y * 64 + blockIdx.x] = red[0] + red[1] + red[2] + red[3];
}

// Reduce all slots: out = err/2 + 0.1/2 * regsum.
__global__ __launch_bounds__(256) void finalize_kernel(
    const float* __restrict__ ws, float* __restrict__ out)
{
  __shared__ float sh[256];
  const int tid = threadIdx.x;
  float e = 0.f, r = 0.f;
  for (int i = tid; i < ERR_SLOTS; i += 256) e += ws[i];
  for (int i = REGA_BASE + tid; i < SLOTS_END; i += 256) r += ws[i];
  sh[tid] = 0.5f * e + 0.05f * r;
  __syncthreads();
  #pragma unroll
  for (int s = 128; s > 0; s >>= 1) {
    if (tid < s) sh[tid] += sh[tid + s];
    __syncthreads();
  }
  if (tid == 0) out[0] = sh[0];
}

extern "C" void kernel_launch(void* const* d_in, const int* in_sizes, int n_in,
                              void* d_out, int out_size, void* d_ws, size_t ws_size,
                              hipStream_t stream) {
  const float* R = (const float*)d_in[0];
  const float* U = (const float*)d_in[1];
  const float* V = (const float*)d_in[2];
  // d_in[3]=alpha, d_in[4]=Y, d_in[6]=Q: dead w.r.t. the returned value.
  const float* P = (const float*)d_in[5];

  float* ws = (float*)d_ws;                                           // slots
  unsigned short* Abf = (unsigned short*)((char*)d_ws + (1 << 20));   // 4 MiB
  unsigned short* Vbf = Abf + (size_t)N_U * KD;                       // 4 MiB
  float* out = (float*)d_out;

  pack_a_kernel<<<dim3(N_U / 64, KD / 64), 256, 0, stream>>>(U, P, Abf, ws);
  pack_v_kernel<<<dim3((N_I * KD) / (256 * 4)), 256, 0, stream>>>(V, Vbf, ws);
  gemm_loss_kernel<<<dim3(64, 64), 256, 0, stream>>>(R, Abf, Vbf, ws);
  finalize_kernel<<<1, 256, 0, stream>>>(ws, out);
}